// Round 7
// baseline (131.912 us; speedup 1.0000x reference)
//
#include <hip/hip_runtime.h>
#include <hip/hip_fp16.h>

// GCN-style symmetric-normalized CSR aggregation.
// out[d][f] = sum_e feat[col_idx[e]][f] * rsqrt(deg[d]*deg[col_idx[e]])
//
// Two passes:
//   pass 1: feath[s][f] = fp16( feat[s][f] * rsqrt(deg[s]) )  (12.8MB in d_ws)
//   pass 2: one wave per dest row, 8 slots x 8 lanes; lane k of a slot loads
//           16B of the slot-edge's 128B fp16 row => 1 inst = 8 edges.
//
// Round-7 deltas vs r6 (mixed latency/inst regime; sectors at fp16 floor):
//   - col_idx loaded directly per-slot (8 dup lanes coalesce) -- removes the
//     2x ds_permute distribution stage from the per-iteration dependency chain.
//   - block=128 (2 waves): halves block-tail imbalance from exponential degree
//     skew, raising effective waves/CU.
//   - conv pass: grid-stride, nontemporal fp32 loads (keep L2 for the table).

typedef float    v4f __attribute__((ext_vector_type(4)));
typedef unsigned v4u __attribute__((ext_vector_type(4)));

// ---------------- pass 1: fold rsqrt(deg[src]) and convert to fp16 ----------
__global__ __launch_bounds__(256) void conv_fold(
    const v4f* __restrict__ in, const float* __restrict__ deg,
    uint2* __restrict__ out, int n4)
{
    const int stride = gridDim.x * blockDim.x;
    for (int i = blockIdx.x * blockDim.x + threadIdx.x; i < n4; i += stride) {
        const float w = rsqrtf(deg[i >> 4]);          // 16 x float4 per 64-float row
        const v4f f = __builtin_nontemporal_load(in + i);
        union { __half2 h; unsigned u; } a, b;
        a.h = __floats2half2_rn(f.x * w, f.y * w);
        b.h = __floats2half2_rn(f.z * w, f.w * w);
        out[i] = make_uint2(a.u, b.u);                // regular store: warm L2 with table
    }
}

// ---------------- pass 2: gather + aggregate --------------------------------
__global__ __launch_bounds__(128) void gcn_gather(
    const int* __restrict__ row_ptr,
    const int* __restrict__ col_idx,
    const unsigned* __restrict__ feath,   // fp16, weight-folded, 128B rows
    const float* __restrict__ deg,
    float* __restrict__ out,
    int n_nodes)
{
    const int row = (blockIdx.x * 128 + threadIdx.x) >> 6;
    if (row >= n_nodes) return;
    const int lane = threadIdx.x & 63;
    const int slot = lane >> 3;        // edge slot 0..7
    const int kb   = (lane & 7) << 4;  // 16B chunk within the 128B row

    const int start = row_ptr[row];
    const int n     = row_ptr[row + 1] - start;   // may be 0 -> store zeros
    const int nm1   = n - 1;
    const char* hbase = (const char*)feath;

    float acc[8] = {0.f, 0.f, 0.f, 0.f, 0.f, 0.f, 0.f, 0.f};

    for (int base = 0; base < n; base += 16) {
        const int e0 = base + slot;
        const int e1 = e0 + 8;
        // Direct per-slot index loads: 8 dup lanes coalesce to 1 request.
        // Chain is col -> gather (no shfl stage).
        const int s0 = col_idx[start + min(e0, nm1)];
        const int s1 = col_idx[start + min(e1, nm1)];
        const v4u q0 = *reinterpret_cast<const v4u*>(hbase + (((unsigned)s0) << 7) + kb);
        const v4u q1 = *reinterpret_cast<const v4u*>(hbase + (((unsigned)s1) << 7) + kb);
        const float w0 = (e0 < n) ? 1.f : 0.f;
        const float w1 = (e1 < n) ? 1.f : 0.f;
#pragma unroll
        for (int p = 0; p < 4; ++p) {
            union { unsigned u; __half2 h; } c0, c1;
            c0.u = q0[p]; c1.u = q1[p];
            const float2 f0 = __half22float2(c0.h);
            const float2 f1 = __half22float2(c1.h);
            acc[2 * p]     += w0 * f0.x + w1 * f1.x;
            acc[2 * p + 1] += w0 * f0.y + w1 * f1.y;
        }
    }

    // Reduce across the 8 slots (lane bits 3,4,5).
#pragma unroll
    for (int m = 8; m <= 32; m <<= 1) {
#pragma unroll
        for (int i = 0; i < 8; ++i) acc[i] += __shfl_xor(acc[i], m);
    }

    if (slot == 0) {
        const float dinv = rsqrtf(deg[row]);   // deg clamped >= 1 by setup
        v4f lo = {acc[0] * dinv, acc[1] * dinv, acc[2] * dinv, acc[3] * dinv};
        v4f hi = {acc[4] * dinv, acc[5] * dinv, acc[6] * dinv, acc[7] * dinv};
        char* po = (char*)out + (((unsigned)row) << 8) + ((lane & 7) << 5);
        __builtin_nontemporal_store(lo, reinterpret_cast<v4f*>(po));
        __builtin_nontemporal_store(hi, reinterpret_cast<v4f*>(po + 16));
    }
}

// ---------------- fallback: fp32 gather (round-3 kernel) --------------------
__global__ __launch_bounds__(256) void gcn_csr_agg_f(
    const int* __restrict__ row_ptr,
    const int* __restrict__ col_idx,
    const float* __restrict__ feat,
    const float* __restrict__ deg,
    float* __restrict__ out,
    int n_nodes)
{
    const int gtid = blockIdx.x * blockDim.x + threadIdx.x;
    const int row  = gtid >> 6;
    if (row >= n_nodes) return;
    const int lane = threadIdx.x & 63;
    const int sub  = lane >> 4;
    const int fbyte = (lane & 15) << 4;

    const int start = row_ptr[row];
    const int end   = row_ptr[row + 1];
    const int last  = end - 1;
    const float dinv = rsqrtf(deg[row]);
    const char* fbase = (const char*)feat;

    v4f acc = {0.f, 0.f, 0.f, 0.f};

    for (int eb = start; eb < end; eb += 16) {
        int e[4]; int s[4]; float d[4]; v4f f[4];
#pragma unroll
        for (int u = 0; u < 4; ++u) {
            e[u] = eb + sub + 4 * u;
            const int c = min(e[u], last);
            s[u] = col_idx[c];
        }
#pragma unroll
        for (int u = 0; u < 4; ++u) {
            d[u] = deg[s[u]];
            const unsigned off = ((unsigned)s[u] << 8) + fbyte;
            f[u] = *reinterpret_cast<const v4f*>(fbase + off);
        }
#pragma unroll
        for (int u = 0; u < 4; ++u) {
            const float w = (e[u] <= last) ? dinv * rsqrtf(d[u]) : 0.f;
            acc += w * f[u];
        }
    }

    acc.x += __shfl_xor(acc.x, 16); acc.y += __shfl_xor(acc.y, 16);
    acc.z += __shfl_xor(acc.z, 16); acc.w += __shfl_xor(acc.w, 16);
    acc.x += __shfl_xor(acc.x, 32); acc.y += __shfl_xor(acc.y, 32);
    acc.z += __shfl_xor(acc.z, 32); acc.w += __shfl_xor(acc.w, 32);

    if (sub == 0) {
        v4f* po = reinterpret_cast<v4f*>((char*)out + ((unsigned)row << 8) + fbyte);
        __builtin_nontemporal_store(acc, po);
    }
}

extern "C" void kernel_launch(void* const* d_in, const int* in_sizes, int n_in,
                              void* d_out, int out_size, void* d_ws, size_t ws_size,
                              hipStream_t stream) {
    const int*   row_ptr = (const int*)d_in[0];
    const int*   col_idx = (const int*)d_in[1];
    const float* feat    = (const float*)d_in[2];
    const float* deg     = (const float*)d_in[3];
    float*       out     = (float*)d_out;

    const int n_nodes = in_sizes[0] - 1;
    const int n_feat_elems = in_sizes[2];            // n_nodes * 64
    const size_t h_bytes = (size_t)n_feat_elems * 2; // fp16 copy size

    if (ws_size >= h_bytes) {
        const int n4 = n_feat_elems >> 2;
        conv_fold<<<1024, 256, 0, stream>>>(
            (const v4f*)feat, deg, (uint2*)d_ws, n4);
        const int grid = (n_nodes + 1) / 2;          // 2 rows (waves) per block
        gcn_gather<<<grid, 128, 0, stream>>>(
            row_ptr, col_idx, (const unsigned*)d_ws, deg, out, n_nodes);
    } else {
        const long long threads = (long long)n_nodes * 64;
        const int grid = (int)((threads + 255) / 256);
        gcn_csr_agg_f<<<grid, 256, 0, stream>>>(
            row_ptr, col_idx, feat, deg, out, n_nodes);
    }
}